// Round 1
// baseline (17.412 us; speedup 1.0000x reference)
//
#include <hip/hip_runtime.h>
#include <hip/hip_bf16.h>

// HypeEntropyModelSoS: symbols = argmin_l |(x - means) - codebook[l]|,
//                      dequant = codebook[symbols] + means
// codebook is SORTED (L=64) -> branchless binary search (lower_bound) + exact
// 2-candidate compare reproduces argmin first-tie semantics exactly in f32.

#define LVLS 64

__global__ __launch_bounds__(256) void quant_sos_kernel(
    const float* __restrict__ x,
    const float* __restrict__ means,
    const float* __restrict__ codebook,
    float* __restrict__ out_sym,   // symbols written as float values
    float* __restrict__ out_deq,
    int n4)                        // number of float4 chunks
{
    __shared__ float cb[LVLS];
    if (threadIdx.x < LVLS) cb[threadIdx.x] = codebook[threadIdx.x];
    __syncthreads();

    const float4* __restrict__ x4 = (const float4*)x;
    const float4* __restrict__ m4 = (const float4*)means;
    float4* __restrict__ s4 = (float4*)out_sym;
    float4* __restrict__ d4 = (float4*)out_deq;

    int tid    = blockIdx.x * blockDim.x + threadIdx.x;
    int stride = gridDim.x * blockDim.x;

    for (int i = tid; i < n4; i += stride) {
        float4 xv = x4[i];
        float4 mv = m4[i];
        float z[4]  = {xv.x - mv.x, xv.y - mv.y, xv.z - mv.z, xv.w - mv.w};
        float mm[4] = {mv.x, mv.y, mv.z, mv.w};
        float sym[4], deq[4];

#pragma unroll
        for (int j = 0; j < 4; ++j) {
            float zj = z[j];
            // branchless lower_bound: pos = #elements with cb[k] < zj
            int pos = 0;
#pragma unroll
            for (int step = 32; step >= 1; step >>= 1) {
                pos = (cb[pos + step - 1] < zj) ? (pos + step) : pos;
            }
            // candidates pos-1 and pos, clamped; exact f32 distance compare,
            // tie -> lower index (matches jnp.argmin first-min semantics)
            int lo = (pos > 0)    ? pos - 1 : 0;
            int hi = (pos < LVLS) ? pos     : LVLS - 1;
            float clo = cb[lo];
            float chi = cb[hi];
            float dlo = fabsf(zj - clo);
            float dhi = fabsf(zj - chi);
            int   idx;
            float cval;
            if (dhi < dlo) { idx = hi; cval = chi; }
            else           { idx = lo; cval = clo; }
            sym[j] = (float)idx;
            deq[j] = cval + mm[j];
        }

        s4[i] = make_float4(sym[0], sym[1], sym[2], sym[3]);
        d4[i] = make_float4(deq[0], deq[1], deq[2], deq[3]);
    }
}

extern "C" void kernel_launch(void* const* d_in, const int* in_sizes, int n_in,
                              void* d_out, int out_size, void* d_ws, size_t ws_size,
                              hipStream_t stream) {
    const float* x        = (const float*)d_in[0];
    const float* means    = (const float*)d_in[1];
    const float* codebook = (const float*)d_in[2];

    int n  = in_sizes[0];          // 4,718,592 (divisible by 4)
    int n4 = n >> 2;

    float* out_sym = (float*)d_out;        // first n floats: symbols (as float)
    float* out_deq = (float*)d_out + n;    // next n floats: dequant

    int block = 256;
    int grid  = (n4 + block - 1) / block;
    if (grid > 2048) grid = 2048;          // grid-stride the rest

    quant_sos_kernel<<<grid, block, 0, stream>>>(x, means, codebook,
                                                 out_sym, out_deq, n4);
}